// Round 2
// baseline (1115.341 us; speedup 1.0000x reference)
//
#include <hip/hip_runtime.h>
#include <math.h>

// Problem constants (match reference)
#define BB 4
#define CC 256
#define HH 128
#define WW 128
#define MM 8
#define PP 4
#define DD 32
#define LQ 16384  // HH*WW

// ---------------------------------------------------------------------------
// K1: value[b][lq][c] = sum_ci collab[b][ci][lq] * Wv[ci][c] + bv[c]
// Output layout [B][Lq][C] (c contiguous) so K3's bilinear gathers are float4.
// Block: 256 threads handles tile of 64 lq x 256 c. collab tile staged in LDS.
// ---------------------------------------------------------------------------
__global__ __launch_bounds__(256) void k_value(
    const float* __restrict__ collab, const float* __restrict__ Wv,
    const float* __restrict__ bv, float* __restrict__ value)
{
  __shared__ float sc[CC][64];  // 64 KB
  const int b   = blockIdx.y;
  const int lq0 = blockIdx.x * 64;
  const int t   = threadIdx.x;

  // Stage collab[b][0..255][lq0..lq0+64) — coalesced float4 rows.
  {
    const int l4    = (t & 15) * 4;
    const int cbase = t >> 4;  // 0..15
    #pragma unroll
    for (int it = 0; it < 16; ++it) {
      const int ci = it * 16 + cbase;
      const float4 v = *(const float4*)(collab + ((size_t)(b * CC + ci)) * LQ + lq0 + l4);
      *(float4*)(&sc[ci][l4]) = v;
    }
  }
  __syncthreads();

  // Thread computes 8 lq x 8 c. c0 varies fastest across lanes (L1-friendly W reads).
  const int c0 = (t & 31) * 8;
  const int l0 = (t >> 5) * 8;

  float acc[8][8];
  #pragma unroll
  for (int i = 0; i < 8; ++i)
    #pragma unroll
    for (int j = 0; j < 8; ++j) acc[i][j] = 0.f;

  for (int ci = 0; ci < CC; ++ci) {
    const float4 a0 = *(const float4*)(&sc[ci][l0]);
    const float4 a1 = *(const float4*)(&sc[ci][l0 + 4]);
    const float4 w0 = *(const float4*)(Wv + (size_t)ci * CC + c0);
    const float4 w1 = *(const float4*)(Wv + (size_t)ci * CC + c0 + 4);
    const float a[8] = {a0.x, a0.y, a0.z, a0.w, a1.x, a1.y, a1.z, a1.w};
    const float w[8] = {w0.x, w0.y, w0.z, w0.w, w1.x, w1.y, w1.z, w1.w};
    #pragma unroll
    for (int i = 0; i < 8; ++i)
      #pragma unroll
      for (int j = 0; j < 8; ++j) acc[i][j] = fmaf(a[i], w[j], acc[i][j]);
  }

  const float4 b0 = *(const float4*)(bv + c0);
  const float4 b1 = *(const float4*)(bv + c0 + 4);
  const float wb[8] = {b0.x, b0.y, b0.z, b0.w, b1.x, b1.y, b1.z, b1.w};
  #pragma unroll
  for (int i = 0; i < 8; ++i) {
    float4 o0, o1;
    o0.x = acc[i][0] + wb[0]; o0.y = acc[i][1] + wb[1];
    o0.z = acc[i][2] + wb[2]; o0.w = acc[i][3] + wb[3];
    o1.x = acc[i][4] + wb[4]; o1.y = acc[i][5] + wb[5];
    o1.z = acc[i][6] + wb[6]; o1.w = acc[i][7] + wb[7];
    float* dst = value + ((size_t)(b * LQ) + lq0 + l0 + i) * CC + c0;
    *(float4*)dst       = o0;
    *(float4*)(dst + 4) = o1;
  }
}

// ---------------------------------------------------------------------------
// K2: per query lq: off = q@W_off + b_off (64), logits = q@W_attn + b_attn (32),
// softmax over P, then SCRAMBLED grid coords (the reference's (2,P)->(P,2)
// reshape quirk; exact with H==W==128):
//   p'=0: (w+o0, w+o2)  p'=1: (w+o4, w+o6)  p'=2: (h+o1, h+o3)  p'=3: (h+o5, h+o7)
// Attn weight for sample p' is attn[p'] (both use the same final axis).
// Stores la[b][lq][m][p'][3] = {gx_pix, gy_pix, attn_weight} as 3 float4s.
// Thread per lq; W rows are wave-uniform -> scalar loads.
// ---------------------------------------------------------------------------
__global__ __launch_bounds__(256) void k_offattn(
    const float* __restrict__ ego, const float* __restrict__ Wo,
    const float* __restrict__ bo, const float* __restrict__ Wa,
    const float* __restrict__ ba, float* __restrict__ la)
{
  const int b  = blockIdx.y;
  const int lq = blockIdx.x * 256 + threadIdx.x;

  float ao[64];
  float aa[32];
  #pragma unroll
  for (int j = 0; j < 64; ++j) ao[j] = 0.f;
  #pragma unroll
  for (int k = 0; k < 32; ++k) aa[k] = 0.f;

  const float* egob = ego + (size_t)b * CC * LQ + lq;
  #pragma unroll 2
  for (int ci = 0; ci < CC; ++ci) {
    const float q = egob[(size_t)ci * LQ];  // coalesced across lanes
    const float* wo = Wo + ci * 64;         // wave-uniform row
    const float* wa = Wa + ci * 32;
    #pragma unroll
    for (int j = 0; j < 64; ++j) ao[j] = fmaf(q, wo[j], ao[j]);
    #pragma unroll
    for (int k = 0; k < 32; ++k) aa[k] = fmaf(q, wa[k], aa[k]);
  }

  const int h = lq >> 7;
  const int w = lq & (WW - 1);
  const float fw = (float)w, fh = (float)h;
  float* outp = la + ((size_t)(b * LQ) + lq) * (MM * PP * 3);

  #pragma unroll
  for (int m = 0; m < MM; ++m) {
    float lg[4];
    #pragma unroll
    for (int p = 0; p < 4; ++p) lg[p] = aa[m * 4 + p] + ba[m * 4 + p];
    const float mx = fmaxf(fmaxf(lg[0], lg[1]), fmaxf(lg[2], lg[3]));
    float e[4];
    float s = 0.f;
    #pragma unroll
    for (int p = 0; p < 4; ++p) { e[p] = expf(lg[p] - mx); s += e[p]; }
    const float inv = 1.0f / s;

    float o[8];
    #pragma unroll
    for (int j = 0; j < 8; ++j) o[j] = ao[m * 8 + j] + bo[m * 8 + j];

    // 12 floats per head: [gx,gy,aw] x 4 points, written as 3 aligned float4s
    // (outp + m*12 is 48B-aligned => 16B-aligned).
    const float gx[4] = {fw + o[0], fw + o[4], fh + o[1], fh + o[5]};
    const float gy[4] = {fw + o[2], fw + o[6], fh + o[3], fh + o[7]};
    const float aw[4] = {e[0] * inv, e[1] * inv, e[2] * inv, e[3] * inv};
    float4 s0, s1, s2;
    s0.x = gx[0]; s0.y = gy[0]; s0.z = aw[0]; s0.w = gx[1];
    s1.x = gy[1]; s1.y = aw[1]; s1.z = gx[2]; s1.w = gy[2];
    s2.x = aw[2]; s2.y = gx[3]; s2.z = gy[3]; s2.w = aw[3];
    float* mp = outp + m * 12;
    *(float4*)(mp + 0) = s0;
    *(float4*)(mp + 4) = s1;
    *(float4*)(mp + 8) = s2;
  }
}

// ---------------------------------------------------------------------------
// K3 (fused sample + output GEMM + residual), block = 64 lq tile of one batch.
// Phase B: wave covers 8m x 8sub(4ch) for ONE lq -> gathers are 8 contiguous
//   128B segments per corner load. Results into LDS tmp[64][256] with XOR
//   swizzle (col ^ (row&31)) so phase-C stride-256 reads are conflict-free
//   (<=2-way, free per m136). Write side pays ~8-way on 64 b32 writes/thread;
//   reads outnumber writes 4:1 so the swizzle optimizes the read side.
// Phase C: thread t: lq = t&63 (coalesced stores), co chunk = 64*(t>>6).
//   out[b][co][lq] = sum_ci tmp[lq][ci]*W_out[ci][co] + b_out[co] + ego[b][co][lq]
// ---------------------------------------------------------------------------
__global__ __launch_bounds__(256) void k_sample_out(
    const float* __restrict__ value, const float* __restrict__ la,
    const float* __restrict__ Wt, const float* __restrict__ bt,
    const float* __restrict__ ego, float* __restrict__ out)
{
  __shared__ float tmp[64][256];  // 64 KB, XOR-swizzled columns
  const int b   = blockIdx.y;
  const int lq0 = blockIdx.x * 64;
  const int t   = threadIdx.x;

  // ---- Phase B: bilinear sampling ----
  {
    const int sub = t & 7;
    const int m   = (t >> 3) & 7;
    const int wv  = t >> 6;  // wave id 0..3
    const int cc  = m * 32 + sub * 4;
    for (int it = 0; it < 16; ++it) {
      const int ll = it * 4 + wv;
      const float* pla = la + (((size_t)(b * LQ) + lq0 + ll) * MM + m) * (PP * 3);
      // 12 floats = 3 aligned float4 loads
      const float4 q0 = *(const float4*)(pla + 0);
      const float4 q1 = *(const float4*)(pla + 4);
      const float4 q2 = *(const float4*)(pla + 8);
      const float gxa[4] = {q0.x, q0.w, q1.z, q2.y};
      const float gya[4] = {q0.y, q1.x, q1.w, q2.z};
      const float awa[4] = {q0.z, q1.y, q2.x, q2.w};

      float a0 = 0.f, a1 = 0.f, a2 = 0.f, a3 = 0.f;
      #pragma unroll
      for (int p = 0; p < PP; ++p) {
        const float gx = gxa[p];
        const float gy = gya[p];
        const float aw = awa[p];
        const float fx0 = floorf(gx), fy0 = floorf(gy);
        const float wx1 = gx - fx0, wy1 = gy - fy0;
        const int ix0 = (int)fx0, iy0 = (int)fy0;
        const float w00 = aw * (1.f - wx1) * (1.f - wy1);
        const float w10 = aw * wx1 * (1.f - wy1);
        const float w01 = aw * (1.f - wx1) * wy1;
        const float w11 = aw * wx1 * wy1;
        // 4 corners, zero padding outside
        {
          const int ix = ix0, iy = iy0;
          if (ix >= 0 && ix < WW && iy >= 0 && iy < HH) {
            const float4 v = *(const float4*)(value + ((size_t)(b * LQ) + iy * WW + ix) * CC + cc);
            a0 = fmaf(w00, v.x, a0); a1 = fmaf(w00, v.y, a1);
            a2 = fmaf(w00, v.z, a2); a3 = fmaf(w00, v.w, a3);
          }
        }
        {
          const int ix = ix0 + 1, iy = iy0;
          if (ix >= 0 && ix < WW && iy >= 0 && iy < HH) {
            const float4 v = *(const float4*)(value + ((size_t)(b * LQ) + iy * WW + ix) * CC + cc);
            a0 = fmaf(w10, v.x, a0); a1 = fmaf(w10, v.y, a1);
            a2 = fmaf(w10, v.z, a2); a3 = fmaf(w10, v.w, a3);
          }
        }
        {
          const int ix = ix0, iy = iy0 + 1;
          if (ix >= 0 && ix < WW && iy >= 0 && iy < HH) {
            const float4 v = *(const float4*)(value + ((size_t)(b * LQ) + iy * WW + ix) * CC + cc);
            a0 = fmaf(w01, v.x, a0); a1 = fmaf(w01, v.y, a1);
            a2 = fmaf(w01, v.z, a2); a3 = fmaf(w01, v.w, a3);
          }
        }
        {
          const int ix = ix0 + 1, iy = iy0 + 1;
          if (ix >= 0 && ix < WW && iy >= 0 && iy < HH) {
            const float4 v = *(const float4*)(value + ((size_t)(b * LQ) + iy * WW + ix) * CC + cc);
            a0 = fmaf(w11, v.x, a0); a1 = fmaf(w11, v.y, a1);
            a2 = fmaf(w11, v.z, a2); a3 = fmaf(w11, v.w, a3);
          }
        }
      }
      const int sw = ll & 31;
      tmp[ll][(cc + 0) ^ sw] = a0;
      tmp[ll][(cc + 1) ^ sw] = a1;
      tmp[ll][(cc + 2) ^ sw] = a2;
      tmp[ll][(cc + 3) ^ sw] = a3;
    }
  }
  __syncthreads();

  // ---- Phase C: out-projection GEMM + bias + residual ----
  const int ll  = t & 63;
  const int co0 = (t >> 6) * 64;
  const int sw  = ll & 31;

  float acc[64];
  #pragma unroll
  for (int j = 0; j < 64; ++j) acc[j] = 0.f;

  for (int ci = 0; ci < CC; ++ci) {
    const float a = tmp[ll][ci ^ sw];
    const float* wr = Wt + (size_t)ci * CC + co0;
    #pragma unroll
    for (int j4 = 0; j4 < 16; ++j4) {
      const float4 wv4 = *(const float4*)(wr + j4 * 4);
      acc[j4 * 4 + 0] = fmaf(a, wv4.x, acc[j4 * 4 + 0]);
      acc[j4 * 4 + 1] = fmaf(a, wv4.y, acc[j4 * 4 + 1]);
      acc[j4 * 4 + 2] = fmaf(a, wv4.z, acc[j4 * 4 + 2]);
      acc[j4 * 4 + 3] = fmaf(a, wv4.w, acc[j4 * 4 + 3]);
    }
  }

  const int lq = lq0 + ll;
  #pragma unroll
  for (int j = 0; j < 64; ++j) {
    const int co = co0 + j;
    const size_t idx = ((size_t)(b * CC) + co) * LQ + lq;
    out[idx] = acc[j] + bt[co] + ego[idx];
  }
}

// ---------------------------------------------------------------------------
extern "C" void kernel_launch(void* const* d_in, const int* in_sizes, int n_in,
                              void* d_out, int out_size, void* d_ws, size_t ws_size,
                              hipStream_t stream) {
  (void)in_sizes; (void)n_in; (void)out_size; (void)ws_size;
  const float* ego    = (const float*)d_in[0];
  const float* collab = (const float*)d_in[1];
  const float* W_off  = (const float*)d_in[2];
  const float* b_off  = (const float*)d_in[3];
  const float* W_attn = (const float*)d_in[4];
  const float* b_attn = (const float*)d_in[5];
  const float* W_val  = (const float*)d_in[6];
  const float* b_val  = (const float*)d_in[7];
  const float* W_out  = (const float*)d_in[8];
  const float* b_out  = (const float*)d_in[9];
  float* out = (float*)d_out;

  // Workspace: value [B][Lq][C] (67.1 MB) then la [B][Lq][M][P][3] (25.2 MB)
  float* value = (float*)d_ws;
  float* la    = value + (size_t)BB * LQ * CC;

  k_value<<<dim3(LQ / 64, BB), 256, 0, stream>>>(collab, W_val, b_val, value);
  k_offattn<<<dim3(LQ / 256, BB), 256, 0, stream>>>(ego, W_off, b_off, W_attn, b_attn, la);
  k_sample_out<<<dim3(LQ / 64, BB), 256, 0, stream>>>(value, la, W_out, b_out, ego, out);
}

// Round 3
// 672.553 us; speedup vs baseline: 1.6584x; 1.6584x over previous
//
#include <hip/hip_runtime.h>
#include <math.h>

// Problem constants (match reference)
#define BB 4
#define CC 256
#define HH 128
#define WW 128
#define MM 8
#define PP 4
#define DD 32
#define LQ 16384  // HH*WW

typedef float f4v __attribute__((ext_vector_type(4)));

// ---------------------------------------------------------------------------
// K1: value[b][lq][c] = sum_ci collab[b][ci][lq] * Wv[ci][c] + bv[c]
// Output layout [B][Lq][C] (c contiguous) so K3's bilinear gathers are float4.
// 256 threads; tile 64 lq x 256 c. collab staged in LDS in TWO 128-ci halves
// (32 KB) -> 4 blocks/CU, 16 waves/CU (was 2 blocks / 8 waves at 64 KB).
// ---------------------------------------------------------------------------
__global__ __launch_bounds__(256) void k_value(
    const float* __restrict__ collab, const float* __restrict__ Wv,
    const float* __restrict__ bv, float* __restrict__ value)
{
  __shared__ float sc[128][64];  // 32 KB
  const int b   = blockIdx.y;
  const int lq0 = blockIdx.x * 64;
  const int t   = threadIdx.x;

  // Thread computes 8 lq x 8 c.
  const int c0 = (t & 31) * 8;
  const int l0 = (t >> 5) * 8;

  float acc[8][8];
  #pragma unroll
  for (int i = 0; i < 8; ++i)
    #pragma unroll
    for (int j = 0; j < 8; ++j) acc[i][j] = 0.f;

  const int l4    = (t & 15) * 4;
  const int cbase = t >> 4;  // 0..15

  for (int h = 0; h < 2; ++h) {
    __syncthreads();
    // Stage collab[b][h*128 .. h*128+127][lq0..lq0+64) — coalesced float4.
    #pragma unroll
    for (int it = 0; it < 8; ++it) {
      const int ci = it * 16 + cbase;  // 0..127
      *(float4*)(&sc[ci][l4]) =
          *(const float4*)(collab + ((size_t)(b * CC + h * 128 + ci)) * LQ + lq0 + l4);
    }
    __syncthreads();

    for (int ci = 0; ci < 128; ++ci) {
      const float4 a0 = *(const float4*)(&sc[ci][l0]);
      const float4 a1 = *(const float4*)(&sc[ci][l0 + 4]);
      const float4 w0 = *(const float4*)(Wv + (size_t)(h * 128 + ci) * CC + c0);
      const float4 w1 = *(const float4*)(Wv + (size_t)(h * 128 + ci) * CC + c0 + 4);
      const float a[8] = {a0.x, a0.y, a0.z, a0.w, a1.x, a1.y, a1.z, a1.w};
      const float w[8] = {w0.x, w0.y, w0.z, w0.w, w1.x, w1.y, w1.z, w1.w};
      #pragma unroll
      for (int i = 0; i < 8; ++i)
        #pragma unroll
        for (int j = 0; j < 8; ++j) acc[i][j] = fmaf(a[i], w[j], acc[i][j]);
    }
  }

  const float4 b0 = *(const float4*)(bv + c0);
  const float4 b1 = *(const float4*)(bv + c0 + 4);
  const float wb[8] = {b0.x, b0.y, b0.z, b0.w, b1.x, b1.y, b1.z, b1.w};
  #pragma unroll
  for (int i = 0; i < 8; ++i) {
    float4 o0, o1;
    o0.x = acc[i][0] + wb[0]; o0.y = acc[i][1] + wb[1];
    o0.z = acc[i][2] + wb[2]; o0.w = acc[i][3] + wb[3];
    o1.x = acc[i][4] + wb[4]; o1.y = acc[i][5] + wb[5];
    o1.z = acc[i][6] + wb[6]; o1.w = acc[i][7] + wb[7];
    float* dst = value + ((size_t)(b * LQ) + lq0 + l0 + i) * CC + c0;
    *(float4*)dst       = o0;
    *(float4*)(dst + 4) = o1;
  }
}

// ---------------------------------------------------------------------------
// K2: off = q@W_off + b_off, logits = q@W_attn + b_attn, softmax over P, then
// SCRAMBLED grid coords (reference's (2,P)->(P,2) reshape; exact w/ H==W==128):
//   p'=0: (w+o0, w+o2)  p'=1: (w+o4, w+o6)  p'=2: (h+o1, h+o3)  p'=3: (h+o5, h+o7)
// Stores la[b][lq][m][p'][3] = {gx_pix, gy_pix, attn_w} as 3 float4s/head.
// NEW: 128-lq tile staged in LDS (32 KB, 4 ci-quarters); 2 threads per lq
// split the 96 outputs by head-halves (t>>7). 512 blocks -> 8 waves/CU
// (was 256 blocks = 4 waves/CU with 256 strided HBM loads per thread).
// W rows stay wave-uniform -> scalar loads.
// ---------------------------------------------------------------------------
__global__ __launch_bounds__(256) void k_offattn(
    const float* __restrict__ ego, const float* __restrict__ Wo,
    const float* __restrict__ bo, const float* __restrict__ Wa,
    const float* __restrict__ ba, float* __restrict__ la)
{
  __shared__ float sq[64][128];  // 32 KB
  const int b    = blockIdx.y;
  const int lq0  = blockIdx.x * 128;
  const int t    = threadIdx.x;
  const int l    = t & 127;   // lq offset in tile
  const int half = t >> 7;    // 0: heads 0-3, 1: heads 4-7 (wave-uniform)

  float ao[32];  // offsets for 4 heads
  float aa[16];  // logits for 4 heads
  #pragma unroll
  for (int j = 0; j < 32; ++j) ao[j] = 0.f;
  #pragma unroll
  for (int k = 0; k < 16; ++k) aa[k] = 0.f;

  const int r0 = t >> 5;        // 0..7
  const int c4 = (t & 31) * 4;  // 0..124

  for (int qi = 0; qi < 4; ++qi) {
    __syncthreads();
    // Stage ego[b][qi*64 .. qi*64+63][lq0..lq0+128) — coalesced float4.
    #pragma unroll
    for (int it = 0; it < 8; ++it) {
      const int r = it * 8 + r0;  // 0..63
      *(float4*)(&sq[r][c4]) =
          *(const float4*)(ego + ((size_t)(b * CC) + qi * 64 + r) * LQ + lq0 + c4);
    }
    __syncthreads();

    const float* wo = Wo + (size_t)(qi * 64) * 64 + half * 32;
    const float* wa = Wa + (size_t)(qi * 64) * 32 + half * 16;
    for (int ci = 0; ci < 64; ++ci) {
      const float q = sq[ci][l];
      #pragma unroll
      for (int j = 0; j < 32; ++j) ao[j] = fmaf(q, wo[ci * 64 + j], ao[j]);
      #pragma unroll
      for (int k = 0; k < 16; ++k) aa[k] = fmaf(q, wa[ci * 32 + k], aa[k]);
    }
  }

  const int lq = lq0 + l;
  const int h  = lq >> 7;
  const int w  = lq & (WW - 1);
  const float fw = (float)w, fh = (float)h;
  float* outp = la + ((size_t)(b * LQ) + lq) * (MM * PP * 3);

  #pragma unroll
  for (int mm = 0; mm < 4; ++mm) {
    const int m = half * 4 + mm;
    float lg[4];
    #pragma unroll
    for (int p = 0; p < 4; ++p) lg[p] = aa[mm * 4 + p] + ba[m * 4 + p];
    const float mx = fmaxf(fmaxf(lg[0], lg[1]), fmaxf(lg[2], lg[3]));
    float e[4];
    float s = 0.f;
    #pragma unroll
    for (int p = 0; p < 4; ++p) { e[p] = expf(lg[p] - mx); s += e[p]; }
    const float inv = 1.0f / s;

    float o[8];
    #pragma unroll
    for (int j = 0; j < 8; ++j) o[j] = ao[mm * 8 + j] + bo[m * 8 + j];

    const float gx[4] = {fw + o[0], fw + o[4], fh + o[1], fh + o[5]};
    const float gy[4] = {fw + o[2], fw + o[6], fh + o[3], fh + o[7]};
    const float aw[4] = {e[0] * inv, e[1] * inv, e[2] * inv, e[3] * inv};
    float4 s0, s1, s2;
    s0.x = gx[0]; s0.y = gy[0]; s0.z = aw[0]; s0.w = gx[1];
    s1.x = gy[1]; s1.y = aw[1]; s1.z = gx[2]; s1.w = gy[2];
    s2.x = aw[2]; s2.y = gx[3]; s2.z = gy[3]; s2.w = aw[3];
    float* mp = outp + m * 12;
    *(float4*)(mp + 0) = s0;
    *(float4*)(mp + 4) = s1;
    *(float4*)(mp + 8) = s2;
  }
}

// ---------------------------------------------------------------------------
// K3 (fused sample + output GEMM + residual). Tile = 32 lq of one batch,
// LDS tmp[32][256] = 32 KB -> 4-5 blocks/CU (~16-20 waves, was 8).
// LDS layout: logical (row,col) stored at col ^ ((row&7)<<2) — float4-
// preserving XOR swizzle; phase-B float4 writes stay contiguous, phase-C
// reads are conflict-free (8 distinct float4 bank-groups tile 32 banks).
// Phase B: wave = (sub 0..7 channels x m 0..7 heads), one lq row per wave
//   per iter. Branchless gathers: clamp indices, fold validity into weights,
//   loads batched 2 points (8 float4) at a time for vmcnt pipelining.
// Phase C: thread = 4 lq (stride 8) x 8 co, ci unrolled x4:
//   4 LDS b128 + 8 global b128 per 128 FMA.
// ---------------------------------------------------------------------------
__global__ __launch_bounds__(256) void k_sample_out(
    const float* __restrict__ value, const float* __restrict__ la,
    const float* __restrict__ Wt, const float* __restrict__ bt,
    const float* __restrict__ ego, float* __restrict__ out)
{
  __shared__ float tmp[32][256];  // 32 KB
  const int b   = blockIdx.y;
  const int lq0 = blockIdx.x * 32;
  const int t   = threadIdx.x;

  // ---- Phase B: bilinear sampling ----
  {
    const int sub = t & 7;
    const int m   = (t >> 3) & 7;
    const int wv  = t >> 6;  // wave id 0..3
    const int cc  = m * 32 + sub * 4;
    const float* vb = value + (size_t)b * LQ * CC + cc;

    #pragma unroll
    for (int it = 0; it < 8; ++it) {
      const int ll = it * 4 + wv;  // 0..31
      const float* pla = la + (((size_t)(b * LQ) + lq0 + ll) * MM + m) * (PP * 3);
      const float4 q0 = *(const float4*)(pla + 0);
      const float4 q1 = *(const float4*)(pla + 4);
      const float4 q2 = *(const float4*)(pla + 8);
      const float gxa[4] = {q0.x, q0.w, q1.z, q2.y};
      const float gya[4] = {q0.y, q1.x, q1.w, q2.z};
      const float awa[4] = {q0.z, q1.y, q2.x, q2.w};

      float a0 = 0.f, a1 = 0.f, a2 = 0.f, a3 = 0.f;

      // Process points in pairs: 8 unconditional loads in flight per pair.
      #pragma unroll
      for (int pp2 = 0; pp2 < 2; ++pp2) {
        int   offs[2][4];
        float wts[2][4];
        #pragma unroll
        for (int pi = 0; pi < 2; ++pi) {
          const int p = pp2 * 2 + pi;
          const float gx = gxa[p], gy = gya[p], aw = awa[p];
          const float fx0 = floorf(gx), fy0 = floorf(gy);
          const float wx1 = gx - fx0, wy1 = gy - fy0;
          // validity from unclamped coords, folded into 1-D weights
          const float vxl = (fx0 >= 0.f && fx0 <= 127.f) ? 1.f : 0.f;
          const float vxr = (fx0 >= -1.f && fx0 <= 126.f) ? 1.f : 0.f;
          const float vyt = (fy0 >= 0.f && fy0 <= 127.f) ? 1.f : 0.f;
          const float vyb = (fy0 >= -1.f && fy0 <= 126.f) ? 1.f : 0.f;
          // clamped integer coords (clamp in float first: no int-ovf UB)
          const int ixl = (int)fminf(fmaxf(fx0, 0.f), 127.f);
          const int ixr = (int)fminf(fmaxf(fx0 + 1.f, 0.f), 127.f);
          const int iyt = (int)fminf(fmaxf(fy0, 0.f), 127.f);
          const int iyb = (int)fminf(fmaxf(fy0 + 1.f, 0.f), 127.f);
          const float wxl = (1.f - wx1) * vxl, wxr = wx1 * vxr;
          const float wyt = (1.f - wy1) * vyt, wyb = wy1 * vyb;
          const int rT = iyt * WW, rB = iyb * WW;
          offs[pi][0] = (rT + ixl) * CC; wts[pi][0] = aw * wxl * wyt;
          offs[pi][1] = (rT + ixr) * CC; wts[pi][1] = aw * wxr * wyt;
          offs[pi][2] = (rB + ixl) * CC; wts[pi][2] = aw * wxl * wyb;
          offs[pi][3] = (rB + ixr) * CC; wts[pi][3] = aw * wxr * wyb;
        }
        f4v vv[2][4];
        #pragma unroll
        for (int pi = 0; pi < 2; ++pi)
          #pragma unroll
          for (int c = 0; c < 4; ++c)
            vv[pi][c] = *(const f4v*)(vb + offs[pi][c]);
        #pragma unroll
        for (int pi = 0; pi < 2; ++pi)
          #pragma unroll
          for (int c = 0; c < 4; ++c) {
            const float wc = wts[pi][c];
            a0 = fmaf(wc, vv[pi][c][0], a0);
            a1 = fmaf(wc, vv[pi][c][1], a1);
            a2 = fmaf(wc, vv[pi][c][2], a2);
            a3 = fmaf(wc, vv[pi][c][3], a3);
          }
      }

      // float4 LDS write, swizzled column
      const int c_sw = cc ^ ((ll & 7) << 2);
      f4v wr; wr[0] = a0; wr[1] = a1; wr[2] = a2; wr[3] = a3;
      *(f4v*)(&tmp[ll][c_sw]) = wr;
    }
  }
  __syncthreads();

  // ---- Phase C: out-projection GEMM + bias + residual ----
  // Thread: 4 lq rows {(t&7)+8i} x 8 co {(t>>3)*8 ..}.
  const int lr  = t & 7;
  const int co0 = (t >> 3) * 8;
  const int sw  = lr << 2;  // (row&7)<<2 == (t&7)<<2 for all 4 rows

  float acc[4][8];
  #pragma unroll
  for (int i = 0; i < 4; ++i)
    #pragma unroll
    for (int j = 0; j < 8; ++j) acc[i][j] = 0.f;

  for (int ci0 = 0; ci0 < CC; ci0 += 4) {
    f4v pa[4];
    #pragma unroll
    for (int i = 0; i < 4; ++i)
      pa[i] = *(const f4v*)(&tmp[lr + 8 * i][ci0 ^ sw]);
    f4v wv4[4][2];
    #pragma unroll
    for (int j = 0; j < 4; ++j) {
      wv4[j][0] = *(const f4v*)(Wt + (size_t)(ci0 + j) * CC + co0);
      wv4[j][1] = *(const f4v*)(Wt + (size_t)(ci0 + j) * CC + co0 + 4);
    }
    #pragma unroll
    for (int i = 0; i < 4; ++i)
      #pragma unroll
      for (int j = 0; j < 4; ++j) {
        const float a = pa[i][j];
        #pragma unroll
        for (int k = 0; k < 4; ++k) {
          acc[i][k]     = fmaf(a, wv4[j][0][k], acc[i][k]);
          acc[i][4 + k] = fmaf(a, wv4[j][1][k], acc[i][4 + k]);
        }
      }
  }

  const f4v bt0 = *(const f4v*)(bt + co0);
  const f4v bt1 = *(const f4v*)(bt + co0 + 4);
  #pragma unroll
  for (int i = 0; i < 4; ++i) {
    const int lq = lq0 + lr + 8 * i;
    #pragma unroll
    for (int j = 0; j < 8; ++j) {
      const int co = co0 + j;
      const size_t idx = ((size_t)(b * CC) + co) * LQ + lq;
      const float bias = (j < 4) ? bt0[j & 3] : bt1[j & 3];
      out[idx] = acc[i][j] + bias + ego[idx];
    }
  }
}

// ---------------------------------------------------------------------------
extern "C" void kernel_launch(void* const* d_in, const int* in_sizes, int n_in,
                              void* d_out, int out_size, void* d_ws, size_t ws_size,
                              hipStream_t stream) {
  (void)in_sizes; (void)n_in; (void)out_size; (void)ws_size;
  const float* ego    = (const float*)d_in[0];
  const float* collab = (const float*)d_in[1];
  const float* W_off  = (const float*)d_in[2];
  const float* b_off  = (const float*)d_in[3];
  const float* W_attn = (const float*)d_in[4];
  const float* b_attn = (const float*)d_in[5];
  const float* W_val  = (const float*)d_in[6];
  const float* b_val  = (const float*)d_in[7];
  const float* W_out  = (const float*)d_in[8];
  const float* b_out  = (const float*)d_in[9];
  float* out = (float*)d_out;

  // Workspace: value [B][Lq][C] (67.1 MB) then la [B][Lq][M][P][3] (25.2 MB)
  float* value = (float*)d_ws;
  float* la    = value + (size_t)BB * LQ * CC;

  k_value<<<dim3(LQ / 64, BB), 256, 0, stream>>>(collab, W_val, b_val, value);
  k_offattn<<<dim3(LQ / 128, BB), 256, 0, stream>>>(ego, W_off, b_off, W_attn, b_attn, la);
  k_sample_out<<<dim3(LQ / 32, BB), 256, 0, stream>>>(value, la, W_out, b_out, ego, out);
}

// Round 7
// 523.190 us; speedup vs baseline: 2.1318x; 1.2855x over previous
//
#include <hip/hip_runtime.h>
#include <math.h>

// Problem constants (match reference)
#define BB 4
#define CC 256
#define HH 128
#define WW 128
#define MM 8
#define PP 4
#define DD 32
#define LQ 16384  // HH*WW

typedef float f4v __attribute__((ext_vector_type(4)));

// ---------------------------------------------------------------------------
// K1: value[b][lq][c] = sum_ci collab[b][ci][lq] * Wv[ci][c] + bv[c]
// Output layout [B][Lq][C] (c contiguous) so K3's bilinear gathers are float4.
// 256 threads; tile 64 lq x 256 c; collab staged in LDS in two 128-ci halves.
// Inner loop unrolled x2 with W loads hoisted ahead of FMAs (4 b128 in
// flight) to cover L2 latency.
// ---------------------------------------------------------------------------
__global__ __launch_bounds__(256) void k_value(
    const float* __restrict__ collab, const float* __restrict__ Wv,
    const float* __restrict__ bv, float* __restrict__ value)
{
  __shared__ float sc[128][64];  // 32 KB
  const int b   = blockIdx.y;
  const int lq0 = blockIdx.x * 64;
  const int t   = threadIdx.x;

  // Thread computes 8 lq x 8 c.
  const int c0 = (t & 31) * 8;
  const int l0 = (t >> 5) * 8;

  float acc[8][8];
  #pragma unroll
  for (int i = 0; i < 8; ++i)
    #pragma unroll
    for (int j = 0; j < 8; ++j) acc[i][j] = 0.f;

  const int l4    = (t & 15) * 4;
  const int cbase = t >> 4;  // 0..15

  for (int h = 0; h < 2; ++h) {
    __syncthreads();
    // Stage collab[b][h*128 .. h*128+127][lq0..lq0+64) — coalesced float4.
    #pragma unroll
    for (int it = 0; it < 8; ++it) {
      const int ci = it * 16 + cbase;  // 0..127
      *(float4*)(&sc[ci][l4]) =
          *(const float4*)(collab + ((size_t)(b * CC + h * 128 + ci)) * LQ + lq0 + l4);
    }
    __syncthreads();

    for (int ci = 0; ci < 128; ci += 2) {
      // Hoist both iterations' W loads (4 b128 in flight).
      const float4 w0 = *(const float4*)(Wv + (size_t)(h * 128 + ci) * CC + c0);
      const float4 w1 = *(const float4*)(Wv + (size_t)(h * 128 + ci) * CC + c0 + 4);
      const float4 w2 = *(const float4*)(Wv + (size_t)(h * 128 + ci + 1) * CC + c0);
      const float4 w3 = *(const float4*)(Wv + (size_t)(h * 128 + ci + 1) * CC + c0 + 4);
      const float4 a0 = *(const float4*)(&sc[ci][l0]);
      const float4 a1 = *(const float4*)(&sc[ci][l0 + 4]);
      const float4 a2 = *(const float4*)(&sc[ci + 1][l0]);
      const float4 a3 = *(const float4*)(&sc[ci + 1][l0 + 4]);
      {
        const float a[8] = {a0.x, a0.y, a0.z, a0.w, a1.x, a1.y, a1.z, a1.w};
        const float w[8] = {w0.x, w0.y, w0.z, w0.w, w1.x, w1.y, w1.z, w1.w};
        #pragma unroll
        for (int i = 0; i < 8; ++i)
          #pragma unroll
          for (int j = 0; j < 8; ++j) acc[i][j] = fmaf(a[i], w[j], acc[i][j]);
      }
      {
        const float a[8] = {a2.x, a2.y, a2.z, a2.w, a3.x, a3.y, a3.z, a3.w};
        const float w[8] = {w2.x, w2.y, w2.z, w2.w, w3.x, w3.y, w3.z, w3.w};
        #pragma unroll
        for (int i = 0; i < 8; ++i)
          #pragma unroll
          for (int j = 0; j < 8; ++j) acc[i][j] = fmaf(a[i], w[j], acc[i][j]);
      }
    }
  }

  const float4 b0 = *(const float4*)(bv + c0);
  const float4 b1 = *(const float4*)(bv + c0 + 4);
  const float wb[8] = {b0.x, b0.y, b0.z, b0.w, b1.x, b1.y, b1.z, b1.w};
  #pragma unroll
  for (int i = 0; i < 8; ++i) {
    float4 o0, o1;
    o0.x = acc[i][0] + wb[0]; o0.y = acc[i][1] + wb[1];
    o0.z = acc[i][2] + wb[2]; o0.w = acc[i][3] + wb[3];
    o1.x = acc[i][4] + wb[4]; o1.y = acc[i][5] + wb[5];
    o1.z = acc[i][6] + wb[6]; o1.w = acc[i][7] + wb[7];
    float* dst = value + ((size_t)(b * LQ) + lq0 + l0 + i) * CC + c0;
    *(float4*)dst       = o0;
    *(float4*)(dst + 4) = o1;
  }
}

// ---------------------------------------------------------------------------
// K2 (LDS-tiled GEMM): [Lq,256] @ [256, 64+32] per batch.
// Tile = 128 lq x all 96 outputs; 8 chunks of 32 ci. Per chunk, stage:
//   sa[32][128] ego tile (16 KB), so[32][64] W_off (8 KB), swa[32][32]
//   W_attn (4 KB) — all coalesced float4. Inner loop: thread = 4 contiguous
//   lq x one head (8 off + 4 attn accs x 4 lq = 48 accs). Per ci:
//   4 ds_read_b128 (ego fragment conflict-free: lane l starts at bank (4l)%32,
//   lanes 0-7 tile all 32 banks per phase; W reads 2-address broadcast = free)
//   + 48 FMA. No global loads in the hot loop (was the R3 bottleneck:
//   48 per-thread global W loads/ci at 8 waves/CU).
// Epilogue: softmax over P + SCRAMBLED coords (reference's (2,P)->(P,2)
// reshape; exact with H==W==128):
//   p'=0: (w+o0, w+o2)  p'=1: (w+o4, w+o6)  p'=2: (h+o1, h+o3)  p'=3: (h+o5, h+o7)
// Stores la[b][lq][m][p'][3] = {gx_pix, gy_pix, attn_w} as 3 float4s/head.
// ---------------------------------------------------------------------------
__global__ __launch_bounds__(256) void k_offattn(
    const float* __restrict__ ego, const float* __restrict__ Wo,
    const float* __restrict__ bo, const float* __restrict__ Wa,
    const float* __restrict__ ba, float* __restrict__ la)
{
  __shared__ float sa[32][128];  // 16 KB
  __shared__ float so[32][64];   //  8 KB
  __shared__ float swa[32][32];  //  4 KB
  const int b    = blockIdx.y;
  const int lq0  = blockIdx.x * 128;
  const int t    = threadIdx.x;
  const int lsub = t & 31;  // lq = lq0 + lsub*4 + i
  const int m    = t >> 5;  // head 0..7 (uniform per 32-lane half-wave)

  float ao[4][8];
  float aa[4][4];
  #pragma unroll
  for (int i = 0; i < 4; ++i) {
    #pragma unroll
    for (int j = 0; j < 8; ++j) ao[i][j] = 0.f;
    #pragma unroll
    for (int p = 0; p < 4; ++p) aa[i][p] = 0.f;
  }

  for (int chunk = 0; chunk < 8; ++chunk) {
    __syncthreads();
    // Stage ego chunk: rows chunk*32+r, 128 lq wide.
    {
      const int r0 = t >> 5;        // 0..7
      const int c4 = (t & 31) * 4;  // 0..124
      #pragma unroll
      for (int it = 0; it < 4; ++it) {
        const int r = it * 8 + r0;
        *(float4*)(&sa[r][c4]) =
            *(const float4*)(ego + ((size_t)(b * CC) + chunk * 32 + r) * LQ + lq0 + c4);
      }
    }
    // Stage W_off chunk: 32 rows x 64.
    {
      const int r0 = t >> 4;        // 0..15
      const int c4 = (t & 15) * 4;  // 0..60
      #pragma unroll
      for (int it = 0; it < 2; ++it) {
        const int r = it * 16 + r0;
        *(float4*)(&so[r][c4]) = *(const float4*)(Wo + (size_t)(chunk * 32 + r) * 64 + c4);
      }
    }
    // Stage W_attn chunk: 32 rows x 32.
    {
      const int r  = t >> 3;       // 0..31
      const int c4 = (t & 7) * 4;  // 0..28
      *(float4*)(&swa[r][c4]) = *(const float4*)(Wa + (size_t)(chunk * 32 + r) * 32 + c4);
    }
    __syncthreads();

    #pragma unroll 4
    for (int ci = 0; ci < 32; ++ci) {
      const f4v q   = *(const f4v*)(&sa[ci][lsub * 4]);
      const f4v wo0 = *(const f4v*)(&so[ci][m * 8]);
      const f4v wo1 = *(const f4v*)(&so[ci][m * 8 + 4]);
      const f4v wa4 = *(const f4v*)(&swa[ci][m * 4]);
      #pragma unroll
      for (int i = 0; i < 4; ++i) {
        const float qq = q[i];
        #pragma unroll
        for (int j = 0; j < 4; ++j) {
          ao[i][j]     = fmaf(qq, wo0[j], ao[i][j]);
          ao[i][4 + j] = fmaf(qq, wo1[j], ao[i][4 + j]);
          aa[i][j]     = fmaf(qq, wa4[j], aa[i][j]);
        }
      }
    }
  }

  // Epilogue: bias + softmax + coord scramble + store (per head m, 4 lqs).
  const f4v bo0 = *(const f4v*)(bo + m * 8);
  const f4v bo1 = *(const f4v*)(bo + m * 8 + 4);
  const f4v ba0 = *(const f4v*)(ba + m * 4);

  #pragma unroll
  for (int i = 0; i < 4; ++i) {
    const int lq = lq0 + lsub * 4 + i;
    const int h  = lq >> 7;
    const int w  = lq & (WW - 1);
    const float fw = (float)w, fh = (float)h;

    float lg[4];
    #pragma unroll
    for (int p = 0; p < 4; ++p) lg[p] = aa[i][p] + ba0[p];
    const float mx = fmaxf(fmaxf(lg[0], lg[1]), fmaxf(lg[2], lg[3]));
    float e[4];
    float s = 0.f;
    #pragma unroll
    for (int p = 0; p < 4; ++p) { e[p] = expf(lg[p] - mx); s += e[p]; }
    const float inv = 1.0f / s;

    float o[8];
    #pragma unroll
    for (int j = 0; j < 4; ++j) { o[j] = ao[i][j] + bo0[j]; o[4 + j] = ao[i][4 + j] + bo1[j]; }

    const float gx[4] = {fw + o[0], fw + o[4], fh + o[1], fh + o[5]};
    const float gy[4] = {fw + o[2], fw + o[6], fh + o[3], fh + o[7]};
    const float aw[4] = {e[0] * inv, e[1] * inv, e[2] * inv, e[3] * inv};
    float4 s0, s1, s2;
    s0.x = gx[0]; s0.y = gy[0]; s0.z = aw[0]; s0.w = gx[1];
    s1.x = gy[1]; s1.y = aw[1]; s1.z = gx[2]; s1.w = gy[2];
    s2.x = aw[2]; s2.y = gx[3]; s2.z = gy[3]; s2.w = aw[3];
    float* mp = la + ((size_t)(b * LQ) + lq) * (MM * PP * 3) + m * 12;
    *(float4*)(mp + 0) = s0;
    *(float4*)(mp + 4) = s1;
    *(float4*)(mp + 8) = s2;
  }
}

// ---------------------------------------------------------------------------
// K3 (fused sample + output GEMM + residual). Tile = 32 lq of one batch,
// LDS tmp[32][256] = 32 KB. XOR swizzle col ^ ((row&7)<<2) keeps float4
// writes contiguous and makes phase-C stride-256 reads conflict-free.
// Phase B: branchless clamped gathers, validity folded into weights, loads
//   batched 2 points (8 float4) at a time.
// Phase C: thread = 4 lq (stride 8) x 8 co, ci unrolled x4.
// ---------------------------------------------------------------------------
__global__ __launch_bounds__(256) void k_sample_out(
    const float* __restrict__ value, const float* __restrict__ la,
    const float* __restrict__ Wt, const float* __restrict__ bt,
    const float* __restrict__ ego, float* __restrict__ out)
{
  __shared__ float tmp[32][256];  // 32 KB
  const int b   = blockIdx.y;
  const int lq0 = blockIdx.x * 32;
  const int t   = threadIdx.x;

  // ---- Phase B: bilinear sampling ----
  {
    const int sub = t & 7;
    const int m   = (t >> 3) & 7;
    const int wv  = t >> 6;  // wave id 0..3
    const int cc  = m * 32 + sub * 4;
    const float* vb = value + (size_t)b * LQ * CC + cc;

    #pragma unroll
    for (int it = 0; it < 8; ++it) {
      const int ll = it * 4 + wv;  // 0..31
      const float* pla = la + (((size_t)(b * LQ) + lq0 + ll) * MM + m) * (PP * 3);
      const float4 q0 = *(const float4*)(pla + 0);
      const float4 q1 = *(const float4*)(pla + 4);
      const float4 q2 = *(const float4*)(pla + 8);
      const float gxa[4] = {q0.x, q0.w, q1.z, q2.y};
      const float gya[4] = {q0.y, q1.x, q1.w, q2.z};
      const float awa[4] = {q0.z, q1.y, q2.x, q2.w};

      float a0 = 0.f, a1 = 0.f, a2 = 0.f, a3 = 0.f;

      #pragma unroll
      for (int pp2 = 0; pp2 < 2; ++pp2) {
        int   offs[2][4];
        float wts[2][4];
        #pragma unroll
        for (int pi = 0; pi < 2; ++pi) {
          const int p = pp2 * 2 + pi;
          const float gx = gxa[p], gy = gya[p], aw = awa[p];
          const float fx0 = floorf(gx), fy0 = floorf(gy);
          const float wx1 = gx - fx0, wy1 = gy - fy0;
          const float vxl = (fx0 >= 0.f && fx0 <= 127.f) ? 1.f : 0.f;
          const float vxr = (fx0 >= -1.f && fx0 <= 126.f) ? 1.f : 0.f;
          const float vyt = (fy0 >= 0.f && fy0 <= 127.f) ? 1.f : 0.f;
          const float vyb = (fy0 >= -1.f && fy0 <= 126.f) ? 1.f : 0.f;
          const int ixl = (int)fminf(fmaxf(fx0, 0.f), 127.f);
          const int ixr = (int)fminf(fmaxf(fx0 + 1.f, 0.f), 127.f);
          const int iyt = (int)fminf(fmaxf(fy0, 0.f), 127.f);
          const int iyb = (int)fminf(fmaxf(fy0 + 1.f, 0.f), 127.f);
          const float wxl = (1.f - wx1) * vxl, wxr = wx1 * vxr;
          const float wyt = (1.f - wy1) * vyt, wyb = wy1 * vyb;
          const int rT = iyt * WW, rB = iyb * WW;
          offs[pi][0] = (rT + ixl) * CC; wts[pi][0] = aw * wxl * wyt;
          offs[pi][1] = (rT + ixr) * CC; wts[pi][1] = aw * wxr * wyt;
          offs[pi][2] = (rB + ixl) * CC; wts[pi][2] = aw * wxl * wyb;
          offs[pi][3] = (rB + ixr) * CC; wts[pi][3] = aw * wxr * wyb;
        }
        f4v vv[2][4];
        #pragma unroll
        for (int pi = 0; pi < 2; ++pi)
          #pragma unroll
          for (int c = 0; c < 4; ++c)
            vv[pi][c] = *(const f4v*)(vb + offs[pi][c]);
        #pragma unroll
        for (int pi = 0; pi < 2; ++pi)
          #pragma unroll
          for (int c = 0; c < 4; ++c) {
            const float wc = wts[pi][c];
            a0 = fmaf(wc, vv[pi][c][0], a0);
            a1 = fmaf(wc, vv[pi][c][1], a1);
            a2 = fmaf(wc, vv[pi][c][2], a2);
            a3 = fmaf(wc, vv[pi][c][3], a3);
          }
      }

      const int c_sw = cc ^ ((ll & 7) << 2);
      f4v wr; wr[0] = a0; wr[1] = a1; wr[2] = a2; wr[3] = a3;
      *(f4v*)(&tmp[ll][c_sw]) = wr;
    }
  }
  __syncthreads();

  // ---- Phase C: out-projection GEMM + bias + residual ----
  const int lr  = t & 7;
  const int co0 = (t >> 3) * 8;
  const int sw  = lr << 2;

  float acc[4][8];
  #pragma unroll
  for (int i = 0; i < 4; ++i)
    #pragma unroll
    for (int j = 0; j < 8; ++j) acc[i][j] = 0.f;

  for (int ci0 = 0; ci0 < CC; ci0 += 4) {
    f4v pa[4];
    #pragma unroll
    for (int i = 0; i < 4; ++i)
      pa[i] = *(const f4v*)(&tmp[lr + 8 * i][ci0 ^ sw]);
    f4v wv4[4][2];
    #pragma unroll
    for (int j = 0; j < 4; ++j) {
      wv4[j][0] = *(const f4v*)(Wt + (size_t)(ci0 + j) * CC + co0);
      wv4[j][1] = *(const f4v*)(Wt + (size_t)(ci0 + j) * CC + co0 + 4);
    }
    #pragma unroll
    for (int i = 0; i < 4; ++i)
      #pragma unroll
      for (int j = 0; j < 4; ++j) {
        const float a = pa[i][j];
        #pragma unroll
        for (int k = 0; k < 4; ++k) {
          acc[i][k]     = fmaf(a, wv4[j][0][k], acc[i][k]);
          acc[i][4 + k] = fmaf(a, wv4[j][1][k], acc[i][4 + k]);
        }
      }
  }

  const f4v bt0 = *(const f4v*)(bt + co0);
  const f4v bt1 = *(const f4v*)(bt + co0 + 4);
  #pragma unroll
  for (int i = 0; i < 4; ++i) {
    const int lq = lq0 + lr + 8 * i;
    #pragma unroll
    for (int j = 0; j < 8; ++j) {
      const int co = co0 + j;
      const size_t idx = ((size_t)(b * CC) + co) * LQ + lq;
      const float bias = (j < 4) ? bt0[j & 3] : bt1[j & 3];
      out[idx] = acc[i][j] + bias + ego[idx];
    }
  }
}

// ---------------------------------------------------------------------------
extern "C" void kernel_launch(void* const* d_in, const int* in_sizes, int n_in,
                              void* d_out, int out_size, void* d_ws, size_t ws_size,
                              hipStream_t stream) {
  (void)in_sizes; (void)n_in; (void)out_size; (void)ws_size;
  const float* ego    = (const float*)d_in[0];
  const float* collab = (const float*)d_in[1];
  const float* W_off  = (const float*)d_in[2];
  const float* b_off  = (const float*)d_in[3];
  const float* W_attn = (const float*)d_in[4];
  const float* b_attn = (const float*)d_in[5];
  const float* W_val  = (const float*)d_in[6];
  const float* b_val  = (const float*)d_in[7];
  const float* W_out  = (const float*)d_in[8];
  const float* b_out  = (const float*)d_in[9];
  float* out = (float*)d_out;

  // Workspace: value [B][Lq][C] (67.1 MB) then la [B][Lq][M][P][3] (25.2 MB)
  float* value = (float*)d_ws;
  float* la    = value + (size_t)BB * LQ * CC;

  k_value<<<dim3(LQ / 64, BB), 256, 0, stream>>>(collab, W_val, b_val, value);
  k_offattn<<<dim3(LQ / 128, BB), 256, 0, stream>>>(ego, W_off, b_off, W_attn, b_attn, la);
  k_sample_out<<<dim3(LQ / 32, BB), 256, 0, stream>>>(value, la, W_out, b_out, ego, out);
}

// Round 9
// 485.920 us; speedup vs baseline: 2.2953x; 1.0767x over previous
//
#include <hip/hip_runtime.h>
#include <math.h>

// Problem constants (match reference)
#define BB 4
#define CC 256
#define HH 128
#define WW 128
#define MM 8
#define PP 4
#define DD 32
#define LQ 16384  // HH*WW

typedef float f4v __attribute__((ext_vector_type(4)));

// ---------------------------------------------------------------------------
// K1 (REWRITTEN): value[b][lq][c] = sum_ci collab[b][ci][lq]*Wv[ci][c] + bv[c]
// Output layout [B][Lq][C] (c contiguous) so K3's bilinear gathers are float4.
// Tile 64 lq x 256 c; K-loop = 8 chunks of 32 ci with BOTH operands in LDS:
//   sw_[32][256] W chunk (32 KB) + sc[32][64] collab chunk (8 KB) = 40 KB
//   -> exactly 4 blocks/CU (160/40). No global loads in the hot loop
//   (R7 evidence: global-W streaming left K1 latency-bound at ~243 us, same
//   signature K2 had pre-rewrite).
// Thread -> output map: c = {4s..4s+3} u {4s+128..4s+131}, s=t&31; lq rows
//   l0=(t>>5)*8. W LDS read = 32 lanes x contiguous float4 (512 B) ->
//   conflict-free (the old c0=(t&31)*8 map would be 8-way conflicted);
//   collab read = 4-address broadcast (free). Per ci: 4 free b128 + 64 FMA.
// ---------------------------------------------------------------------------
__global__ __launch_bounds__(256) void k_value(
    const float* __restrict__ collab, const float* __restrict__ Wv,
    const float* __restrict__ bv, float* __restrict__ value)
{
  __shared__ float sw_[32][256];  // 32 KB
  __shared__ float sc[32][64];    //  8 KB
  const int b   = blockIdx.y;
  const int lq0 = blockIdx.x * 64;
  const int t   = threadIdx.x;

  const int c_lo = (t & 31) * 4;  // cols {c_lo..+3} and {c_lo+128..+3}
  const int l0   = (t >> 5) * 8;  // 8 lq rows

  float acc[8][8];  // [lq][c: 0-3 -> c_lo+j, 4-7 -> c_lo+128+j]
  #pragma unroll
  for (int i = 0; i < 8; ++i)
    #pragma unroll
    for (int j = 0; j < 8; ++j) acc[i][j] = 0.f;

  const int wr0 = t >> 6;        // 0..3   (W stage: row base)
  const int wc4 = (t & 63) * 4;  // 0..252 (W stage: col)
  const int cr0 = t >> 4;        // 0..15  (collab stage: row base)
  const int cc4 = (t & 15) * 4;  // 0..60  (collab stage: col)

  for (int ch = 0; ch < 8; ++ch) {
    __syncthreads();
    // Stage W chunk: rows ch*32..+31, all 256 cols. 64 threads cover one
    // 1 KB row -> fully coalesced.
    #pragma unroll
    for (int i = 0; i < 8; ++i) {
      const int r = wr0 + i * 4;
      *(float4*)(&sw_[r][wc4]) =
          *(const float4*)(Wv + (size_t)(ch * 32 + r) * CC + wc4);
    }
    // Stage collab chunk: rows ch*32..+31, 64 lq wide.
    #pragma unroll
    for (int i = 0; i < 2; ++i) {
      const int r = cr0 + i * 16;
      *(float4*)(&sc[r][cc4]) =
          *(const float4*)(collab + ((size_t)(b * CC + ch * 32 + r)) * LQ + lq0 + cc4);
    }
    __syncthreads();

    #pragma unroll 4
    for (int ci = 0; ci < 32; ++ci) {
      const f4v a0 = *(const f4v*)(&sc[ci][l0]);
      const f4v a1 = *(const f4v*)(&sc[ci][l0 + 4]);
      const f4v w0 = *(const f4v*)(&sw_[ci][c_lo]);
      const f4v w1 = *(const f4v*)(&sw_[ci][c_lo + 128]);
      const float a[8] = {a0[0], a0[1], a0[2], a0[3], a1[0], a1[1], a1[2], a1[3]};
      #pragma unroll
      for (int i = 0; i < 8; ++i) {
        #pragma unroll
        for (int j = 0; j < 4; ++j) {
          acc[i][j]     = fmaf(a[i], w0[j], acc[i][j]);
          acc[i][4 + j] = fmaf(a[i], w1[j], acc[i][4 + j]);
        }
      }
    }
  }

  const f4v bv0 = *(const f4v*)(bv + c_lo);
  const f4v bv1 = *(const f4v*)(bv + c_lo + 128);
  #pragma unroll
  for (int i = 0; i < 8; ++i) {
    f4v o0, o1;
    #pragma unroll
    for (int j = 0; j < 4; ++j) {
      o0[j] = acc[i][j] + bv0[j];
      o1[j] = acc[i][4 + j] + bv1[j];
    }
    float* dst = value + ((size_t)(b * LQ) + lq0 + l0 + i) * CC + c_lo;
    *(f4v*)dst         = o0;
    *(f4v*)(dst + 128) = o1;
  }
}

// ---------------------------------------------------------------------------
// K2 (LDS-tiled GEMM): [Lq,256] @ [256, 64+32] per batch.  UNCHANGED
// (233 -> ~84 us measured-by-subtraction; left top-5 in R7).
// Epilogue: softmax over P + SCRAMBLED coords (reference's (2,P)->(P,2)
// reshape; exact with H==W==128):
//   p'=0: (w+o0, w+o2)  p'=1: (w+o4, w+o6)  p'=2: (h+o1, h+o3)  p'=3: (h+o5, h+o7)
// ---------------------------------------------------------------------------
__global__ __launch_bounds__(256) void k_offattn(
    const float* __restrict__ ego, const float* __restrict__ Wo,
    const float* __restrict__ bo, const float* __restrict__ Wa,
    const float* __restrict__ ba, float* __restrict__ la)
{
  __shared__ float sa[32][128];  // 16 KB
  __shared__ float so[32][64];   //  8 KB
  __shared__ float swa[32][32];  //  4 KB
  const int b    = blockIdx.y;
  const int lq0  = blockIdx.x * 128;
  const int t    = threadIdx.x;
  const int lsub = t & 31;  // lq = lq0 + lsub*4 + i
  const int m    = t >> 5;  // head 0..7 (uniform per 32-lane half-wave)

  float ao[4][8];
  float aa[4][4];
  #pragma unroll
  for (int i = 0; i < 4; ++i) {
    #pragma unroll
    for (int j = 0; j < 8; ++j) ao[i][j] = 0.f;
    #pragma unroll
    for (int p = 0; p < 4; ++p) aa[i][p] = 0.f;
  }

  for (int chunk = 0; chunk < 8; ++chunk) {
    __syncthreads();
    {
      const int r0 = t >> 5;        // 0..7
      const int c4 = (t & 31) * 4;  // 0..124
      #pragma unroll
      for (int it = 0; it < 4; ++it) {
        const int r = it * 8 + r0;
        *(float4*)(&sa[r][c4]) =
            *(const float4*)(ego + ((size_t)(b * CC) + chunk * 32 + r) * LQ + lq0 + c4);
      }
    }
    {
      const int r0 = t >> 4;        // 0..15
      const int c4 = (t & 15) * 4;  // 0..60
      #pragma unroll
      for (int it = 0; it < 2; ++it) {
        const int r = it * 16 + r0;
        *(float4*)(&so[r][c4]) = *(const float4*)(Wo + (size_t)(chunk * 32 + r) * 64 + c4);
      }
    }
    {
      const int r  = t >> 3;       // 0..31
      const int c4 = (t & 7) * 4;  // 0..28
      *(float4*)(&swa[r][c4]) = *(const float4*)(Wa + (size_t)(chunk * 32 + r) * 32 + c4);
    }
    __syncthreads();

    #pragma unroll 4
    for (int ci = 0; ci < 32; ++ci) {
      const f4v q   = *(const f4v*)(&sa[ci][lsub * 4]);
      const f4v wo0 = *(const f4v*)(&so[ci][m * 8]);
      const f4v wo1 = *(const f4v*)(&so[ci][m * 8 + 4]);
      const f4v wa4 = *(const f4v*)(&swa[ci][m * 4]);
      #pragma unroll
      for (int i = 0; i < 4; ++i) {
        const float qq = q[i];
        #pragma unroll
        for (int j = 0; j < 4; ++j) {
          ao[i][j]     = fmaf(qq, wo0[j], ao[i][j]);
          ao[i][4 + j] = fmaf(qq, wo1[j], ao[i][4 + j]);
          aa[i][j]     = fmaf(qq, wa4[j], aa[i][j]);
        }
      }
    }
  }

  const f4v bo0 = *(const f4v*)(bo + m * 8);
  const f4v bo1 = *(const f4v*)(bo + m * 8 + 4);
  const f4v ba0 = *(const f4v*)(ba + m * 4);

  #pragma unroll
  for (int i = 0; i < 4; ++i) {
    const int lq = lq0 + lsub * 4 + i;
    const int h  = lq >> 7;
    const int w  = lq & (WW - 1);
    const float fw = (float)w, fh = (float)h;

    float lg[4];
    #pragma unroll
    for (int p = 0; p < 4; ++p) lg[p] = aa[i][p] + ba0[p];
    const float mx = fmaxf(fmaxf(lg[0], lg[1]), fmaxf(lg[2], lg[3]));
    float e[4];
    float s = 0.f;
    #pragma unroll
    for (int p = 0; p < 4; ++p) { e[p] = expf(lg[p] - mx); s += e[p]; }
    const float inv = 1.0f / s;

    float o[8];
    #pragma unroll
    for (int j = 0; j < 4; ++j) { o[j] = ao[i][j] + bo0[j]; o[4 + j] = ao[i][4 + j] + bo1[j]; }

    const float gx[4] = {fw + o[0], fw + o[4], fh + o[1], fh + o[5]};
    const float gy[4] = {fw + o[2], fw + o[6], fh + o[3], fh + o[7]};
    const float aw[4] = {e[0] * inv, e[1] * inv, e[2] * inv, e[3] * inv};
    float4 s0, s1, s2;
    s0.x = gx[0]; s0.y = gy[0]; s0.z = aw[0]; s0.w = gx[1];
    s1.x = gy[1]; s1.y = aw[1]; s1.z = gx[2]; s1.w = gy[2];
    s2.x = aw[2]; s2.y = gx[3]; s2.z = gy[3]; s2.w = aw[3];
    float* mp = la + ((size_t)(b * LQ) + lq) * (MM * PP * 3) + m * 12;
    *(float4*)(mp + 0) = s0;
    *(float4*)(mp + 4) = s1;
    *(float4*)(mp + 8) = s2;
  }
}

// ---------------------------------------------------------------------------
// K3 (fused sample + output GEMM + residual).  UNCHANGED
// (196 us, VALUBusy 51%, bank conflicts 0 in R7).
// ---------------------------------------------------------------------------
__global__ __launch_bounds__(256) void k_sample_out(
    const float* __restrict__ value, const float* __restrict__ la,
    const float* __restrict__ Wt, const float* __restrict__ bt,
    const float* __restrict__ ego, float* __restrict__ out)
{
  __shared__ float tmp[32][256];  // 32 KB
  const int b   = blockIdx.y;
  const int lq0 = blockIdx.x * 32;
  const int t   = threadIdx.x;

  // ---- Phase B: bilinear sampling ----
  {
    const int sub = t & 7;
    const int m   = (t >> 3) & 7;
    const int wv  = t >> 6;  // wave id 0..3
    const int cc  = m * 32 + sub * 4;
    const float* vb = value + (size_t)b * LQ * CC + cc;

    #pragma unroll
    for (int it = 0; it < 8; ++it) {
      const int ll = it * 4 + wv;  // 0..31
      const float* pla = la + (((size_t)(b * LQ) + lq0 + ll) * MM + m) * (PP * 3);
      const float4 q0 = *(const float4*)(pla + 0);
      const float4 q1 = *(const float4*)(pla + 4);
      const float4 q2 = *(const float4*)(pla + 8);
      const float gxa[4] = {q0.x, q0.w, q1.z, q2.y};
      const float gya[4] = {q0.y, q1.x, q1.w, q2.z};
      const float awa[4] = {q0.z, q1.y, q2.x, q2.w};

      float a0 = 0.f, a1 = 0.f, a2 = 0.f, a3 = 0.f;

      #pragma unroll
      for (int pp2 = 0; pp2 < 2; ++pp2) {
        int   offs[2][4];
        float wts[2][4];
        #pragma unroll
        for (int pi = 0; pi < 2; ++pi) {
          const int p = pp2 * 2 + pi;
          const float gx = gxa[p], gy = gya[p], aw = awa[p];
          const float fx0 = floorf(gx), fy0 = floorf(gy);
          const float wx1 = gx - fx0, wy1 = gy - fy0;
          const float vxl = (fx0 >= 0.f && fx0 <= 127.f) ? 1.f : 0.f;
          const float vxr = (fx0 >= -1.f && fx0 <= 126.f) ? 1.f : 0.f;
          const float vyt = (fy0 >= 0.f && fy0 <= 127.f) ? 1.f : 0.f;
          const float vyb = (fy0 >= -1.f && fy0 <= 126.f) ? 1.f : 0.f;
          const int ixl = (int)fminf(fmaxf(fx0, 0.f), 127.f);
          const int ixr = (int)fminf(fmaxf(fx0 + 1.f, 0.f), 127.f);
          const int iyt = (int)fminf(fmaxf(fy0, 0.f), 127.f);
          const int iyb = (int)fminf(fmaxf(fy0 + 1.f, 0.f), 127.f);
          const float wxl = (1.f - wx1) * vxl, wxr = wx1 * vxr;
          const float wyt = (1.f - wy1) * vyt, wyb = wy1 * vyb;
          const int rT = iyt * WW, rB = iyb * WW;
          offs[pi][0] = (rT + ixl) * CC; wts[pi][0] = aw * wxl * wyt;
          offs[pi][1] = (rT + ixr) * CC; wts[pi][1] = aw * wxr * wyt;
          offs[pi][2] = (rB + ixl) * CC; wts[pi][2] = aw * wxl * wyb;
          offs[pi][3] = (rB + ixr) * CC; wts[pi][3] = aw * wxr * wyb;
        }
        f4v vv[2][4];
        #pragma unroll
        for (int pi = 0; pi < 2; ++pi)
          #pragma unroll
          for (int c = 0; c < 4; ++c)
            vv[pi][c] = *(const f4v*)(vb + offs[pi][c]);
        #pragma unroll
        for (int pi = 0; pi < 2; ++pi)
          #pragma unroll
          for (int c = 0; c < 4; ++c) {
            const float wc = wts[pi][c];
            a0 = fmaf(wc, vv[pi][c][0], a0);
            a1 = fmaf(wc, vv[pi][c][1], a1);
            a2 = fmaf(wc, vv[pi][c][2], a2);
            a3 = fmaf(wc, vv[pi][c][3], a3);
          }
      }

      const int c_sw = cc ^ ((ll & 7) << 2);
      f4v wr; wr[0] = a0; wr[1] = a1; wr[2] = a2; wr[3] = a3;
      *(f4v*)(&tmp[ll][c_sw]) = wr;
    }
  }
  __syncthreads();

  // ---- Phase C: out-projection GEMM + bias + residual ----
  const int lr  = t & 7;
  const int co0 = (t >> 3) * 8;
  const int sw  = lr << 2;

  float acc[4][8];
  #pragma unroll
  for (int i = 0; i < 4; ++i)
    #pragma unroll
    for (int j = 0; j < 8; ++j) acc[i][j] = 0.f;

  for (int ci0 = 0; ci0 < CC; ci0 += 4) {
    f4v pa[4];
    #pragma unroll
    for (int i = 0; i < 4; ++i)
      pa[i] = *(const f4v*)(&tmp[lr + 8 * i][ci0 ^ sw]);
    f4v wv4[4][2];
    #pragma unroll
    for (int j = 0; j < 4; ++j) {
      wv4[j][0] = *(const f4v*)(Wt + (size_t)(ci0 + j) * CC + co0);
      wv4[j][1] = *(const f4v*)(Wt + (size_t)(ci0 + j) * CC + co0 + 4);
    }
    #pragma unroll
    for (int i = 0; i < 4; ++i)
      #pragma unroll
      for (int j = 0; j < 4; ++j) {
        const float a = pa[i][j];
        #pragma unroll
        for (int k = 0; k < 4; ++k) {
          acc[i][k]     = fmaf(a, wv4[j][0][k], acc[i][k]);
          acc[i][4 + k] = fmaf(a, wv4[j][1][k], acc[i][4 + k]);
        }
      }
  }

  const f4v bt0 = *(const f4v*)(bt + co0);
  const f4v bt1 = *(const f4v*)(bt + co0 + 4);
  #pragma unroll
  for (int i = 0; i < 4; ++i) {
    const int lq = lq0 + lr + 8 * i;
    #pragma unroll
    for (int j = 0; j < 8; ++j) {
      const int co = co0 + j;
      const size_t idx = ((size_t)(b * CC) + co) * LQ + lq;
      const float bias = (j < 4) ? bt0[j & 3] : bt1[j & 3];
      out[idx] = acc[i][j] + bias + ego[idx];
    }
  }
}

// ---------------------------------------------------------------------------
extern "C" void kernel_launch(void* const* d_in, const int* in_sizes, int n_in,
                              void* d_out, int out_size, void* d_ws, size_t ws_size,
                              hipStream_t stream) {
  (void)in_sizes; (void)n_in; (void)out_size; (void)ws_size;
  const float* ego    = (const float*)d_in[0];
  const float* collab = (const float*)d_in[1];
  const float* W_off  = (const float*)d_in[2];
  const float* b_off  = (const float*)d_in[3];
  const float* W_attn = (const float*)d_in[4];
  const float* b_attn = (const float*)d_in[5];
  const float* W_val  = (const float*)d_in[6];
  const float* b_val  = (const float*)d_in[7];
  const float* W_out  = (const float*)d_in[8];
  const float* b_out  = (const float*)d_in[9];
  float* out = (float*)d_out;

  // Workspace: value [B][Lq][C] (67.1 MB) then la [B][Lq][M][P][3] (25.2 MB)
  float* value = (float*)d_ws;
  float* la    = value + (size_t)BB * LQ * CC;

  k_value<<<dim3(LQ / 64, BB), 256, 0, stream>>>(collab, W_val, b_val, value);
  k_offattn<<<dim3(LQ / 128, BB), 256, 0, stream>>>(ego, W_off, b_off, W_attn, b_attn, la);
  k_sample_out<<<dim3(LQ / 32, BB), 256, 0, stream>>>(value, la, W_out, b_out, ego, out);
}